// Round 4
// baseline (277.050 us; speedup 1.0000x reference)
//
#include <hip/hip_runtime.h>

#define IMW 1024
#define IMH 1024
#define NB  8
#define HALF 25
#define TW 64                    // tile width  (output cols per block)
#define TH 32                    // tile height (output rows per block)
#define HBR (TH + 2*HALF)        // 82 h-rows per tile
#define NCELL 64

#define W_R ((double)0.2989f)
#define W_G ((double)0.5870f)
#define W_B ((double)0.1140f)
#define INV_AREA (1.0 / 2601.0)

__device__ __forceinline__ int refl(int i, int n) {
    if (i < 0) i = -i;
    if (i >= n) i = 2 * n - 2 - i;
    return i;
}

// LDS swizzle: +1 slot per 32 entries. Verified 2-way (free) for both access
// patterns here: phase-1 writes flat=32u+j -> bank (u+j)%32; phase-2 reads
// flat=64r+c (r wave-uniform) -> bank (c+(c>>5))%32.
__device__ __forceinline__ int swz(int p) { return p + (p >> 5); }

// init 64 min-cells (all-ones) and 64 max-cells (zero); g>=0 so f32 bit-order == uint order
__global__ void k0_init(unsigned* cells) {
    cells[threadIdx.x] = (threadIdx.x < NCELL) ? 0xFFFFFFFFu : 0u;
}

// Pure-streaming gray pass: RGB f32 -> gray f32 (f64 dot, rounded once),
// coalesced float4 in/out, hierarchical min/max atomics. No scan, no hp.
__global__ __launch_bounds__(256) void k1_gray(const float* __restrict__ in,
                                               float* __restrict__ gray,
                                               unsigned* __restrict__ cells) {
    __shared__ float bmin[4], bmax[4];
    const int t = threadIdx.x;
    const int lane = t & 63, w = t >> 6;
    const long long gt = (long long)blockIdx.x * 256 + t;   // 4 px per thread

    const float4* p4 = (const float4*)in + 3 * gt;
    float4 f0 = p4[0], f1 = p4[1], f2 = p4[2];
    float g0 = (float)((double)f0.x*W_R + (double)f0.y*W_G + (double)f0.z*W_B);
    float g1 = (float)((double)f0.w*W_R + (double)f1.x*W_G + (double)f1.y*W_B);
    float g2 = (float)((double)f1.z*W_R + (double)f1.w*W_G + (double)f2.x*W_B);
    float g3 = (float)((double)f2.y*W_R + (double)f2.z*W_G + (double)f2.w*W_B);
    ((float4*)gray)[gt] = make_float4(g0, g1, g2, g3);

    float lmin = fminf(fminf(g0, g1), fminf(g2, g3));
    float lmax = fmaxf(fmaxf(g0, g1), fmaxf(g2, g3));
    for (int off = 32; off; off >>= 1) {
        lmin = fminf(lmin, __shfl_down(lmin, off));
        lmax = fmaxf(lmax, __shfl_down(lmax, off));
    }
    if (lane == 0) { bmin[w] = lmin; bmax[w] = lmax; }
    __syncthreads();
    if (t == 0) {
        float m0 = fminf(fminf(bmin[0], bmin[1]), fminf(bmin[2], bmin[3]));
        float m1 = fmaxf(fmaxf(bmax[0], bmax[1]), fmaxf(bmax[2], bmax[3]));
        int cell = blockIdx.x & (NCELL - 1);
        atomicMin(&cells[cell], __float_as_uint(m0));
        atomicMax(&cells[NCELL + cell], __float_as_uint(m1));
    }
}

// Fused box-filter + Sauvola threshold per 64x32 output tile. hp never hits HBM.
// Phase 1 (164 units = 82 h-rows x 2 halves): load the 88-float gray span into
// REGISTERS up front (22 aligned float4 global loads, L2-served; scalar+reflect
// only for x-edge tiles), horizontal 51-slide in f64, write h1/h2 f32 to LDS.
// Phase 2 (64 cols x 4 row-groups): vertical 51-slide over LDS h, threshold,
// coalesced stores. Reflection baked in at fill time (hb[r] = h(refl(y0+r-25)))
// so the vertical window sums compose exactly as the reference's.
// One __syncthreads total. Grid XCD-swizzled: batch = id&7 -> one image per XCD
// (4.2 MB gray slice ~ L2-resident); consecutive ids walk y-tiles (halo share).
__global__ __launch_bounds__(256) void k2_fused(const float* __restrict__ gray,
                                                const unsigned* __restrict__ cells,
                                                float* __restrict__ out) {
    __shared__ float h1b[5412], h2b[5412];   // swz(81*64+63)=5410
    __shared__ double sr[2];
    const int t = threadIdx.x;

    // global r from cells (wave 0)
    if (t < 64) {
        unsigned mn = cells[t];
        unsigned mx = cells[NCELL + t];
        for (int off = 32; off; off >>= 1) {
            unsigned a = __shfl_down(mn, off);
            unsigned b2 = __shfl_down(mx, off);
            mn = (a < mn) ? a : mn;
            mx = (b2 > mx) ? b2 : mx;
        }
        if (t == 0) {
            sr[0] = (double)__uint_as_float(mn);
            sr[1] = (double)__uint_as_float(mx);
        }
    }

    const int id   = blockIdx.x;          // 4096 blocks
    const int b    = id & 7;              // batch -> XCD
    const int rest = id >> 3;
    const int yt   = rest & 31;           // y-tile (consecutive on same XCD)
    const int xt   = rest >> 5;           // x-tile (0..15)
    const int x0 = xt * TW, y0 = yt * TH;
    const long long ib = (long long)b * IMH * IMW;

    // ---- phase 1: horizontal window sums into LDS ----
    if (t < 2 * HBR) {
        const int r  = t >> 1;            // h-row 0..81  (image row refl(y0+r-25))
        const int hh = t & 1;             // half: output cols [32h, 32h+31]
        const int grow = refl(y0 + r - HALF, IMH);
        const float* grp = gray + ib + (long long)grow * IMW;
        const int c0 = x0 + 32 * hh;

        // gr[i] = gray[row][c0-28+i], i in [0,88): covers window span [c0-25, c0+56]
        float gr[88];
        if (x0 == 0 || x0 == IMW - TW) {          // block-uniform branch
            #pragma unroll
            for (int i = 0; i < 88; i++) gr[i] = grp[refl(c0 - 28 + i, IMW)];
        } else {
            const float4* q = (const float4*)(grp + (c0 - 28));   // 16B-aligned
            #pragma unroll
            for (int i = 0; i < 22; i++) {
                float4 f = q[i];
                gr[4*i+0] = f.x; gr[4*i+1] = f.y; gr[4*i+2] = f.z; gr[4*i+3] = f.w;
            }
        }

        // prologue: 51 taps (gr[3..53]), 3 independent f64 accumulators
        double s1a = 0, s1b = 0, s1c = 0, s2a = 0, s2b = 0, s2c = 0;
        #pragma unroll
        for (int i = 3; i < 54; i += 3) {
            double d0 = (double)gr[i], d1 = (double)gr[i+1], d2 = (double)gr[i+2];
            s1a += d0; s2a = fma(d0, d0, s2a);
            s1b += d1; s2b = fma(d1, d1, s2b);
            s1c += d2; s2c = fma(d2, d2, s2c);
        }
        double v1 = (s1a + s1b) + s1c;
        double v2 = (s2a + s2b) + s2c;

        const int hbase = 32 * t;         // = r*64 + 32*hh
        #pragma unroll
        for (int j = 0; j < 32; j++) {
            h1b[swz(hbase + j)] = (float)v1;
            h2b[swz(hbase + j)] = (float)v2;
            if (j != 31) {
                double ga = (double)gr[j + 54], gs = (double)gr[j + 3];
                v1 += ga - gs;
                v2 += ga * ga - gs * gs;   // f32 squares exact in f64
            }
        }
    }
    __syncthreads();

    // ---- phase 2: vertical slide + threshold ----
    const double r  = 0.5 * (sr[1] - sr[0]);
    const double r2 = r * r;
    const int c  = t & 63;                // column (wave = 64 consecutive cols)
    const int g4 = t >> 6;                // row-group: 8 output rows each
    const int r0 = 8 * g4;

    double u1a = 0, u1b = 0, u1c = 0, u2a = 0, u2b = 0, u2c = 0;
    #pragma unroll
    for (int i = 0; i < 51; i += 3) {
        double a0 = (double)h1b[swz((r0 + i    ) * 64 + c)];
        double a1 = (double)h1b[swz((r0 + i + 1) * 64 + c)];
        double a2 = (double)h1b[swz((r0 + i + 2) * 64 + c)];
        u1a += a0; u1b += a1; u1c += a2;
        double b0 = (double)h2b[swz((r0 + i    ) * 64 + c)];
        double b1 = (double)h2b[swz((r0 + i + 1) * 64 + c)];
        double b2 = (double)h2b[swz((r0 + i + 2) * 64 + c)];
        u2a += b0; u2b += b1; u2c += b2;
    }
    double u1 = (u1a + u1b) + u1c;
    double u2 = (u2a + u2b) + u2c;

    #pragma unroll
    for (int j = 0; j < 8; j++) {
        const int yy = y0 + r0 + j;
        const long long pix = ib + (long long)yy * IMW + (x0 + c);
        double gv = (double)gray[pix];     // L2-hot (phase 1 just read this row)
        double m  = u1 * INV_AREA;
        double va = fmax(u2 * INV_AREA - m * m, 0.0);
        double A  = gv - 0.8 * m;
        int o = (A > 0.0) && (A * A * r2 > 0.04 * m * m * va);
        out[pix] = o ? 1.0f : 0.0f;
        if (j != 7) {
            const int rr = r0 + j;
            u1 += (double)h1b[swz((rr + 51) * 64 + c)] - (double)h1b[swz(rr * 64 + c)];
            u2 += (double)h2b[swz((rr + 51) * 64 + c)] - (double)h2b[swz(rr * 64 + c)];
        }
    }
}

extern "C" void kernel_launch(void* const* d_in, const int* in_sizes, int n_in,
                              void* d_out, int out_size, void* d_ws, size_t ws_size,
                              hipStream_t stream) {
    const float* in = (const float*)d_in[0];
    float* out = (float*)d_out;

    unsigned* cells = (unsigned*)d_ws;                 // 2*64 u32
    float* gray = (float*)((char*)d_ws + 4096);        // 33.5 MB staged gray

    hipLaunchKernelGGL(k0_init, dim3(1), dim3(2 * NCELL), 0, stream, cells);
    hipLaunchKernelGGL(k1_gray, dim3(NB * IMH * IMW / 1024), dim3(256), 0, stream,
                       in, gray, cells);
    hipLaunchKernelGGL(k2_fused, dim3(NB * (IMH / TH) * (IMW / TW)), dim3(256), 0, stream,
                       gray, cells, out);
}